// Round 10
// baseline (1000.132 us; speedup 1.0000x reference)
//
#include <hip/hip_runtime.h>
#include <stdint.h>

#define NUM_USER 200000
#define NUM_ITEM 400000
#define NNODES   (NUM_USER + NUM_ITEM)   // 600000
#define D        64
#define NNZ      6000000
#define ND       ((size_t)NNODES * D)    // 38.4e6 elements

#define RPB       512                     // rows per bucket
#define NBUCK     ((NNODES + RPB - 1) / RPB)   // 1172
#define CAP       8192                    // max edges staged per bucket (mean 5119)
#define CHUNK     16384                   // edges per block in coarse scatter

typedef float    f4 __attribute__((ext_vector_type(4)));
typedef uint32_t u4 __attribute__((ext_vector_type(4)));

// ---- bf16 helpers (RNE) ----
__device__ __forceinline__ uint32_t bfr(float f) {
    uint32_t u = __float_as_uint(f);
    return (u + 0x7FFFu + ((u >> 16) & 1u)) >> 16;
}
__device__ __forceinline__ uint32_t pack2(float lo, float hi) {
    return (bfr(hi) << 16) | bfr(lo);
}
__device__ __forceinline__ float bl(uint32_t u) { return __uint_as_float(u << 16); }
__device__ __forceinline__ float bh(uint32_t u) { return __uint_as_float(u & 0xFFFF0000u); }

// ---------------- ego -> two bf16 half-tables ----------------
// Half h holds dims [h*32, h*32+32) for all nodes: T_h[node*4 + slot] (u4 = 8 bf16).
__global__ void k_cvt(const float* __restrict__ uemb, const float* __restrict__ iemb,
                      u4* __restrict__ half0, u4* __restrict__ half1) {
    long long tid = (long long)blockIdx.x * blockDim.x + threadIdx.x;
    if (tid >= (long long)(ND / 8)) return;
    int node = (int)(tid >> 3);
    int seg = (int)(tid & 7);          // 8 fp32-pairs segments of the 64-dim row
    const f4* src = (node < NUM_USER)
        ? (const f4*)uemb + ((size_t)node << 4) + seg * 2
        : (const f4*)iemb + ((size_t)(node - NUM_USER) << 4) + seg * 2;
    f4 a = src[0], b = src[1];
    u4 o;
    o.x = pack2(a.x, a.y); o.y = pack2(a.z, a.w);
    o.z = pack2(b.x, b.y); o.w = pack2(b.z, b.w);
    u4* dst = (seg < 4) ? half0 : half1;
    dst[(size_t)node * 4 + (seg & 3)] = o;
}

// ---------------- CSR build: two-level bucket multisplit ----------------

__global__ void k_coarse_hist(const int* __restrict__ rows, int* __restrict__ bcnt) {
    __shared__ int h[NBUCK];
    for (int i = threadIdx.x; i < NBUCK; i += blockDim.x) h[i] = 0;
    __syncthreads();
    int stride = gridDim.x * blockDim.x;
    for (int e = blockIdx.x * blockDim.x + threadIdx.x; e < NNZ; e += stride)
        atomicAdd(&h[rows[e] >> 9], 1);
    __syncthreads();
    for (int i = threadIdx.x; i < NBUCK; i += blockDim.x)
        if (h[i]) atomicAdd(&bcnt[i], h[i]);
}

__global__ void k_bucket_scan(const int* __restrict__ bcnt, int* __restrict__ bbase,
                              int* __restrict__ bcur, int* __restrict__ row_ptr) {
    __shared__ int tsum[1024];
    int t = threadIdx.x;
    int i0 = 2 * t, i1 = 2 * t + 1;
    int c0 = (i0 < NBUCK) ? bcnt[i0] : 0;
    int c1 = (i1 < NBUCK) ? bcnt[i1] : 0;
    tsum[t] = c0 + c1;
    __syncthreads();
    for (int off = 1; off < 1024; off <<= 1) {
        int v = (t >= off) ? tsum[t - off] : 0;
        __syncthreads();
        tsum[t] += v;
        __syncthreads();
    }
    int excl = (t == 0) ? 0 : tsum[t - 1];
    if (i0 < NBUCK) { bbase[i0] = excl;      bcur[i0] = excl; }
    if (i1 < NBUCK) { bbase[i1] = excl + c0; bcur[i1] = excl + c0; }
    if (t == 0) { bbase[NBUCK] = NNZ; row_ptr[NNODES] = NNZ; }
}

__global__ void k_coarse_scatter(const int* __restrict__ rows, const int* __restrict__ cols,
                                 const float* __restrict__ vals, int* __restrict__ bcur,
                                 uint64_t* __restrict__ edges) {
    __shared__ int cnt[NBUCK];
    __shared__ int start[NBUCK];
    int t = threadIdx.x;
    long long base = (long long)blockIdx.x * CHUNK;
    for (int i = t; i < NBUCK; i += blockDim.x) cnt[i] = 0;
    __syncthreads();
    for (int i = t; i < CHUNK; i += blockDim.x) {
        long long e = base + i;
        if (e < NNZ) atomicAdd(&cnt[rows[e] >> 9], 1);
    }
    __syncthreads();
    for (int b = t; b < NBUCK; b += blockDim.x) {
        int c = cnt[b];
        start[b] = c ? atomicAdd(&bcur[b], c) : 0;
    }
    __syncthreads();
    for (int i = t; i < NBUCK; i += blockDim.x) cnt[i] = 0;  // reuse as cursor
    __syncthreads();
    for (int i = t; i < CHUNK; i += blockDim.x) {
        long long e = base + i;
        if (e >= NNZ) continue;
        int r = rows[e];
        int b = r >> 9;
        int pos = start[b] + atomicAdd(&cnt[b], 1);
        uint64_t packed = ((uint64_t)(uint32_t)__float_as_int(vals[e]) << 32)
                        | ((uint64_t)(r & (RPB - 1)) << 20)
                        | (uint32_t)cols[e];
        edges[pos] = packed;
    }
}

__global__ void k_bucket_sort(const int* __restrict__ bbase, uint64_t* __restrict__ edges,
                              int* __restrict__ row_ptr) {
    __shared__ uint64_t stage[CAP];
    __shared__ int hist[RPB];
    __shared__ int cur[RPB];
    int b = blockIdx.x;
    int t = threadIdx.x;
    int bb = bbase[b];
    int cnt = bbase[b + 1] - bb;
    for (int i = t; i < cnt; i += blockDim.x) stage[i] = edges[bb + i];
    for (int i = t; i < RPB; i += blockDim.x) hist[i] = 0;
    __syncthreads();
    for (int i = t; i < cnt; i += blockDim.x)
        atomicAdd(&hist[(uint32_t)(stage[i] >> 20) & (RPB - 1)], 1);
    __syncthreads();
    for (int off = 1; off < RPB; off <<= 1) {
        int v = (t >= off) ? hist[t - off] : 0;
        __syncthreads();
        hist[t] += v;
        __syncthreads();
    }
    int excl = (t == 0) ? 0 : hist[t - 1];
    long long row = (long long)b * RPB + t;
    if (row < NNODES) row_ptr[row] = bb + excl;
    cur[t] = excl;
    __syncthreads();
    for (int i = t; i < cnt; i += blockDim.x) {
        uint64_t e = stage[i];
        int lr = (uint32_t)(e >> 20) & (RPB - 1);
        int pos = atomicAdd(&cur[lr], 1);
        edges[bb + pos] = (e & 0xFFFFFFFF00000000ull) | (e & 0xFFFFFull);
    }
}

// ---------------- fused pull hop: HALF-D pass, 16 rows/wave ----------------
// Each wave: 16 groups x 4 lanes x 16B = one 64B half-row gather per edge.
// Hot gather set per pass = 38.4 MB (fits LLC with room to spare).
// 8-deep unrolled edge loop. EPI: 1 = +ego from bf16 half-table; 0 = fp32 inputs.
// dst[r, h*32..] = (sum_j v_j * src_h[c_j] + ego_h(r)) * (FINAL ? 0.25 : 1)

template<int EPI, bool FINAL>
__global__ void k_hop(const int* __restrict__ row_ptr,
                      const uint64_t* __restrict__ edges,
                      const u4* __restrict__ src_h,
                      const u4* __restrict__ ego_h,
                      const float* __restrict__ uemb,
                      const float* __restrict__ iemb,
                      void* __restrict__ dst,
                      int h) {
    constexpr int U = 8;
    int wave = (blockIdx.x * blockDim.x + threadIdx.x) >> 6;
    int lane = threadIdx.x & 63;
    int g = lane >> 2;   // row within wave's 16
    int l = lane & 3;    // u4 slot within 64B half-row
    int r = wave * 16 + g;
    bool rv = (r < NNODES);
    int beg = rv ? row_ptr[r] : 0;
    int end = rv ? row_ptr[r + 1] : 0;
    float acc0[8], acc1[8];
    #pragma unroll
    for (int k = 0; k < 8; ++k) { acc0[k] = 0.f; acc1[k] = 0.f; }
    for (int j = beg; ; j += U) {
        if (!__any(j < end)) break;
        uint64_t cv[U];
        bool act[U];
        #pragma unroll
        for (int u = 0; u < U; ++u) {
            act[u] = (j + u < end);
            if (act[u]) cv[u] = edges[j + u];
        }
        u4 s[U];
        #pragma unroll
        for (int u = 0; u < U; ++u) {
            if (act[u]) s[u] = src_h[(size_t)((uint32_t)cv[u] & 0xFFFFFu) * 4 + l];
        }
        #pragma unroll
        for (int u = 0; u < U; ++u) {
            if (act[u]) {
                float v = __int_as_float((int)(cv[u] >> 32));
                float* a = (u & 1) ? acc1 : acc0;
                a[0] += v * bl(s[u].x); a[1] += v * bh(s[u].x);
                a[2] += v * bl(s[u].y); a[3] += v * bh(s[u].y);
                a[4] += v * bl(s[u].z); a[5] += v * bh(s[u].z);
                a[6] += v * bl(s[u].w); a[7] += v * bh(s[u].w);
            }
        }
    }
    if (!rv) return;
    float e[8];
    if (EPI == 1) {
        u4 eg = ego_h[(size_t)r * 4 + l];
        e[0] = bl(eg.x); e[1] = bh(eg.x); e[2] = bl(eg.y); e[3] = bh(eg.y);
        e[4] = bl(eg.z); e[5] = bh(eg.z); e[6] = bl(eg.w); e[7] = bh(eg.w);
    } else {
        const f4* ep = ((r < NUM_USER)
            ? (const f4*)uemb + ((size_t)r << 4)
            : (const f4*)iemb + ((size_t)(r - NUM_USER) << 4)) + h * 8 + l * 2;
        f4 e0 = ep[0], e1 = ep[1];
        e[0] = e0.x; e[1] = e0.y; e[2] = e0.z; e[3] = e0.w;
        e[4] = e1.x; e[5] = e1.y; e[6] = e1.z; e[7] = e1.w;
    }
    float res[8];
    #pragma unroll
    for (int k = 0; k < 8; ++k) res[k] = acc0[k] + acc1[k] + e[k];
    if (FINAL) {
        f4 o0 = {res[0] * 0.25f, res[1] * 0.25f, res[2] * 0.25f, res[3] * 0.25f};
        f4 o1 = {res[4] * 0.25f, res[5] * 0.25f, res[6] * 0.25f, res[7] * 0.25f};
        f4* dp = (f4*)dst + ((size_t)r << 4) + h * 8 + l * 2;
        __builtin_nontemporal_store(o0, dp);
        __builtin_nontemporal_store(o1, dp + 1);
    } else {
        u4 o;
        o.x = pack2(res[0], res[1]); o.y = pack2(res[2], res[3]);
        o.z = pack2(res[4], res[5]); o.w = pack2(res[6], res[7]);
        *((u4*)dst + (size_t)r * 4 + l) = o;   // cached: next hop gathers this
    }
}

extern "C" void kernel_launch(void* const* d_in, const int* in_sizes, int n_in,
                              void* d_out, int out_size, void* d_ws, size_t ws_size,
                              hipStream_t stream) {
    const float* vals = (const float*)d_in[0];
    const float* uemb = (const float*)d_in[1];
    const float* iemb = (const float*)d_in[2];
    const int*   rows = (const int*)d_in[3];
    const int*   cols = rows + NNZ;

    float* out = (float*)d_out;

    // ---- workspace layout; each logical buffer = two half-tables (38.4 MB each) ----
    const size_t HALF_U4 = ND / 16;        // u4 elements per half-table
    size_t off = 0;
    char* ws = (char*)d_ws;
    auto take = [&](size_t bytes) { char* p = ws + off; off += (bytes + 255) & ~(size_t)255; return p; };
    u4*       egoT    = (u4*)take(2 * HALF_U4 * sizeof(u4));   // 76.8 MB
    u4*       X1      = (u4*)take(2 * HALF_U4 * sizeof(u4));   // 76.8 MB
    int*      row_ptr = (int*)take((NNODES + 1) * sizeof(int));
    int*      bcnt    = (int*)take(NBUCK * sizeof(int));
    int*      bbase   = (int*)take((NBUCK + 1) * sizeof(int));
    int*      bcur    = (int*)take(NBUCK * sizeof(int));
    uint64_t* edges   = (uint64_t*)take((size_t)NNZ * sizeof(uint64_t));  // 48 MB
    u4*       X2      = (u4*)take(2 * HALF_U4 * sizeof(u4));   // +76.8 MB (conditional)
    bool three_buf = (off <= ws_size);

    u4* ego_h[2] = { egoT, egoT + HALF_U4 };
    u4* x1_h[2]  = { X1,   X1   + HALF_U4 };
    u4* x2_h[2]  = { X2,   X2   + HALF_U4 };

    // ---- ego -> bf16 half-tables ----
    const long long cvt_threads = ND / 8;
    k_cvt<<<(int)((cvt_threads + 255) / 256), 256, 0, stream>>>(uemb, iemb, ego_h[0], ego_h[1]);

    // ---- build row-sorted edge list ----
    hipMemsetAsync(bcnt, 0, NBUCK * sizeof(int), stream);
    k_coarse_hist<<<512, 512, 0, stream>>>(rows, bcnt);
    k_bucket_scan<<<1, 1024, 0, stream>>>(bcnt, bbase, bcur, row_ptr);
    k_coarse_scatter<<<(NNZ + CHUNK - 1) / CHUNK, 512, 0, stream>>>(rows, cols, vals, bcur, edges);
    k_bucket_sort<<<NBUCK, RPB, 0, stream>>>(bbase, edges, row_ptr);

    // ---- 3 fused hops x 2 half-D passes (Horner) ----
    const int hop_blocks = (NNODES + 63) / 64;   // 16 rows/wave, 4 waves/block
    if (three_buf) {
        for (int h = 0; h < 2; ++h)
            k_hop<1, false><<<hop_blocks, 256, 0, stream>>>(row_ptr, edges, ego_h[h], ego_h[h], uemb, iemb, x1_h[h], h);
        for (int h = 0; h < 2; ++h)
            k_hop<1, false><<<hop_blocks, 256, 0, stream>>>(row_ptr, edges, x1_h[h], ego_h[h], uemb, iemb, x2_h[h], h);
        for (int h = 0; h < 2; ++h)
            k_hop<1, true ><<<hop_blocks, 256, 0, stream>>>(row_ptr, edges, x2_h[h], ego_h[h], uemb, iemb, out, h);
    } else {
        // 2-buffer fallback: hop2 overwrites egoT (its epilogue reads fp32 inputs).
        for (int h = 0; h < 2; ++h)
            k_hop<1, false><<<hop_blocks, 256, 0, stream>>>(row_ptr, edges, ego_h[h], ego_h[h], uemb, iemb, x1_h[h], h);
        for (int h = 0; h < 2; ++h)
            k_hop<0, false><<<hop_blocks, 256, 0, stream>>>(row_ptr, edges, x1_h[h], nullptr, uemb, iemb, ego_h[h], h);
        for (int h = 0; h < 2; ++h)
            k_hop<0, true ><<<hop_blocks, 256, 0, stream>>>(row_ptr, edges, ego_h[h], nullptr, uemb, iemb, out, h);
    }
}

// Round 11
// 716.810 us; speedup vs baseline: 1.3953x; 1.3953x over previous
//
#include <hip/hip_runtime.h>
#include <stdint.h>

#define NUM_USER 200000
#define NUM_ITEM 400000
#define NNODES   (NUM_USER + NUM_ITEM)   // 600000
#define D        64
#define NNZ      6000000
#define ND       ((size_t)NNODES * D)    // 38.4e6 elements

#define RPB       512                     // rows per bucket
#define NBUCK     ((NNODES + RPB - 1) / RPB)   // 1172
#define CAP       8192                    // max edges staged per bucket (mean 5119)
#define CHUNK     8192                    // edges per block in coarse scatter

typedef float    f4 __attribute__((ext_vector_type(4)));
typedef uint32_t u4 __attribute__((ext_vector_type(4)));

// ---- bf16 helpers (RNE) ----
__device__ __forceinline__ uint32_t bfr(float f) {
    uint32_t u = __float_as_uint(f);
    return (u + 0x7FFFu + ((u >> 16) & 1u)) >> 16;
}
__device__ __forceinline__ uint32_t pack2(float lo, float hi) {
    return (bfr(hi) << 16) | bfr(lo);
}
__device__ __forceinline__ float bl(uint32_t u) { return __uint_as_float(u << 16); }
__device__ __forceinline__ float bh(uint32_t u) { return __uint_as_float(u & 0xFFFF0000u); }

// ---------------- ego -> bf16 table (one pass) ----------------
__global__ void k_cvt(const float* __restrict__ uemb, const float* __restrict__ iemb,
                      u4* __restrict__ ego_bf) {
    long long tid = (long long)blockIdx.x * blockDim.x + threadIdx.x;
    if (tid >= (long long)(ND / 8)) return;
    int node = (int)(tid >> 3);
    int seg = (int)(tid & 7);
    const f4* src = (node < NUM_USER)
        ? (const f4*)uemb + ((size_t)node << 4) + seg * 2
        : (const f4*)iemb + ((size_t)(node - NUM_USER) << 4) + seg * 2;
    f4 a = src[0], b = src[1];
    u4 o;
    o.x = pack2(a.x, a.y); o.y = pack2(a.z, a.w);
    o.z = pack2(b.x, b.y); o.w = pack2(b.z, b.w);
    ego_bf[tid] = o;
}

// ---------------- CSR build: two-level bucket multisplit ----------------

__global__ void k_coarse_hist(const int* __restrict__ rows, int* __restrict__ bcnt) {
    __shared__ int h[NBUCK];
    for (int i = threadIdx.x; i < NBUCK; i += blockDim.x) h[i] = 0;
    __syncthreads();
    int stride = gridDim.x * blockDim.x;
    for (int e = blockIdx.x * blockDim.x + threadIdx.x; e < NNZ; e += stride)
        atomicAdd(&h[rows[e] >> 9], 1);
    __syncthreads();
    for (int i = threadIdx.x; i < NBUCK; i += blockDim.x)
        if (h[i]) atomicAdd(&bcnt[i], h[i]);
}

__global__ void k_bucket_scan(const int* __restrict__ bcnt, int* __restrict__ bbase,
                              int* __restrict__ bcur, int* __restrict__ row_ptr) {
    __shared__ int tsum[1024];
    int t = threadIdx.x;
    int i0 = 2 * t, i1 = 2 * t + 1;
    int c0 = (i0 < NBUCK) ? bcnt[i0] : 0;
    int c1 = (i1 < NBUCK) ? bcnt[i1] : 0;
    tsum[t] = c0 + c1;
    __syncthreads();
    for (int off = 1; off < 1024; off <<= 1) {
        int v = (t >= off) ? tsum[t - off] : 0;
        __syncthreads();
        tsum[t] += v;
        __syncthreads();
    }
    int excl = (t == 0) ? 0 : tsum[t - 1];
    if (i0 < NBUCK) { bbase[i0] = excl;      bcur[i0] = excl; }
    if (i1 < NBUCK) { bbase[i1] = excl + c0; bcur[i1] = excl + c0; }
    if (t == 0) { bbase[NBUCK] = NNZ; row_ptr[NNODES] = NNZ; }
}

__global__ void k_coarse_scatter(const int* __restrict__ rows, const int* __restrict__ cols,
                                 const float* __restrict__ vals, int* __restrict__ bcur,
                                 uint64_t* __restrict__ edges) {
    __shared__ int cnt[NBUCK];
    __shared__ int start[NBUCK];
    int t = threadIdx.x;
    long long base = (long long)blockIdx.x * CHUNK;
    for (int i = t; i < NBUCK; i += blockDim.x) cnt[i] = 0;
    __syncthreads();
    for (int i = t; i < CHUNK; i += blockDim.x) {
        long long e = base + i;
        if (e < NNZ) atomicAdd(&cnt[rows[e] >> 9], 1);
    }
    __syncthreads();
    for (int b = t; b < NBUCK; b += blockDim.x) {
        int c = cnt[b];
        start[b] = c ? atomicAdd(&bcur[b], c) : 0;
    }
    __syncthreads();
    for (int i = t; i < NBUCK; i += blockDim.x) cnt[i] = 0;  // reuse as cursor
    __syncthreads();
    for (int i = t; i < CHUNK; i += blockDim.x) {
        long long e = base + i;
        if (e >= NNZ) continue;
        int r = rows[e];
        int b = r >> 9;
        int pos = start[b] + atomicAdd(&cnt[b], 1);
        uint64_t packed = ((uint64_t)(uint32_t)__float_as_int(vals[e]) << 32)
                        | ((uint64_t)(r & (RPB - 1)) << 20)
                        | (uint32_t)cols[e];
        edges[pos] = packed;
    }
}

__global__ void k_bucket_sort(const int* __restrict__ bbase, uint64_t* __restrict__ edges,
                              int* __restrict__ row_ptr) {
    __shared__ uint64_t stage[CAP];
    __shared__ int hist[RPB];
    __shared__ int cur[RPB];
    int b = blockIdx.x;
    int t = threadIdx.x;
    int bb = bbase[b];
    int cnt = bbase[b + 1] - bb;
    for (int i = t; i < cnt; i += blockDim.x) stage[i] = edges[bb + i];
    for (int i = t; i < RPB; i += blockDim.x) hist[i] = 0;
    __syncthreads();
    for (int i = t; i < cnt; i += blockDim.x)
        atomicAdd(&hist[(uint32_t)(stage[i] >> 20) & (RPB - 1)], 1);
    __syncthreads();
    for (int off = 1; off < RPB; off <<= 1) {
        int v = (t >= off) ? hist[t - off] : 0;
        __syncthreads();
        hist[t] += v;
        __syncthreads();
    }
    int excl = (t == 0) ? 0 : hist[t - 1];
    long long row = (long long)b * RPB + t;
    if (row < NNODES) row_ptr[row] = bb + excl;
    cur[t] = excl;
    __syncthreads();
    for (int i = t; i < cnt; i += blockDim.x) {
        uint64_t e = stage[i];
        int lr = (uint32_t)(e >> 20) & (RPB - 1);
        int pos = atomicAdd(&cur[lr], 1);
        edges[bb + pos] = (e & 0xFFFFFFFF00000000ull) | (e & 0xFFFFFull);
    }
}

// ---------------- fused pull hop: 8 rows/wave, 8-deep unrolled gather ----------------
// Factored polynomial (I+A)(I+A^2): each hop's epilogue (if any) reads a table
// already in the hop's live set, keeping every hop's footprint ~202MB < 256MB LLC.
// EPI: 1 = add epi_bf[r] (bf16) in epilogue; 0 = no epilogue add.
// dst[r] = (sum_j v_j * src_bf[c_j] (+ epi_bf[r])) * (FINAL ? 0.25 : 1)

template<int EPI, bool FINAL>
__global__ void k_hop(const int* __restrict__ row_ptr,
                      const uint64_t* __restrict__ edges,
                      const u4* __restrict__ src_bf,
                      const u4* __restrict__ epi_bf,
                      void* __restrict__ dst) {
    constexpr int U = 8;
    int wave = (blockIdx.x * blockDim.x + threadIdx.x) >> 6;
    int lane = threadIdx.x & 63;
    int g = lane >> 3;   // row within wave's 8
    int l = lane & 7;    // 16B slot within 128B bf16 row
    int r = wave * 8 + g;
    bool rv = (r < NNODES);
    int beg = rv ? row_ptr[r] : 0;
    int end = rv ? row_ptr[r + 1] : 0;
    float acc0[8], acc1[8];
    #pragma unroll
    for (int k = 0; k < 8; ++k) { acc0[k] = 0.f; acc1[k] = 0.f; }
    for (int j = beg; ; j += U) {
        if (!__any(j < end)) break;
        uint64_t cv[U];
        bool act[U];
        #pragma unroll
        for (int u = 0; u < U; ++u) {
            act[u] = (j + u < end);
            if (act[u]) cv[u] = edges[j + u];
        }
        u4 s[U];
        #pragma unroll
        for (int u = 0; u < U; ++u) {
            if (act[u]) s[u] = src_bf[((size_t)((uint32_t)cv[u] & 0xFFFFFu) << 3) + l];
        }
        #pragma unroll
        for (int u = 0; u < U; ++u) {
            if (act[u]) {
                float v = __int_as_float((int)(cv[u] >> 32));
                float* a = (u & 1) ? acc1 : acc0;
                a[0] += v * bl(s[u].x); a[1] += v * bh(s[u].x);
                a[2] += v * bl(s[u].y); a[3] += v * bh(s[u].y);
                a[4] += v * bl(s[u].z); a[5] += v * bh(s[u].z);
                a[6] += v * bl(s[u].w); a[7] += v * bh(s[u].w);
            }
        }
    }
    if (!rv) return;
    float res[8];
    #pragma unroll
    for (int k = 0; k < 8; ++k) res[k] = acc0[k] + acc1[k];
    if (EPI == 1) {
        u4 eg = epi_bf[((size_t)r << 3) + l];
        res[0] += bl(eg.x); res[1] += bh(eg.x);
        res[2] += bl(eg.y); res[3] += bh(eg.y);
        res[4] += bl(eg.z); res[5] += bh(eg.z);
        res[6] += bl(eg.w); res[7] += bh(eg.w);
    }
    if (FINAL) {
        f4 o0 = {res[0] * 0.25f, res[1] * 0.25f, res[2] * 0.25f, res[3] * 0.25f};
        f4 o1 = {res[4] * 0.25f, res[5] * 0.25f, res[6] * 0.25f, res[7] * 0.25f};
        f4* dp = (f4*)dst + ((size_t)r << 4) + l * 2;
        __builtin_nontemporal_store(o0, dp);
        __builtin_nontemporal_store(o1, dp + 1);
    } else {
        u4 o;
        o.x = pack2(res[0], res[1]); o.y = pack2(res[2], res[3]);
        o.z = pack2(res[4], res[5]); o.w = pack2(res[6], res[7]);
        *((u4*)dst + ((size_t)r << 3) + l) = o;   // cached: a later hop reads this
    }
}

extern "C" void kernel_launch(void* const* d_in, const int* in_sizes, int n_in,
                              void* d_out, int out_size, void* d_ws, size_t ws_size,
                              hipStream_t stream) {
    const float* vals = (const float*)d_in[0];
    const float* uemb = (const float*)d_in[1];
    const float* iemb = (const float*)d_in[2];
    const int*   rows = (const int*)d_in[3];
    const int*   cols = rows + NNZ;

    float* out = (float*)d_out;

    // ---- workspace layout (~205 MB, proven fit) ----
    size_t off = 0;
    char* ws = (char*)d_ws;
    auto take = [&](size_t bytes) { char* p = ws + off; off += (bytes + 255) & ~(size_t)255; return p; };
    u4*       P       = (u4*)take((ND / 8) * sizeof(u4));   // 76.8 MB: ego, then Z
    u4*       Q       = (u4*)take((ND / 8) * sizeof(u4));   // 76.8 MB: Y
    int*      row_ptr = (int*)take((NNODES + 1) * sizeof(int));
    int*      bcnt    = (int*)take(NBUCK * sizeof(int));
    int*      bbase   = (int*)take((NBUCK + 1) * sizeof(int));
    int*      bcur    = (int*)take(NBUCK * sizeof(int));
    uint64_t* edges   = (uint64_t*)take((size_t)NNZ * sizeof(uint64_t));  // 48 MB
    (void)ws_size;

    // ---- ego -> bf16 table ----
    const long long cvt_threads = ND / 8;
    k_cvt<<<(int)((cvt_threads + 255) / 256), 256, 0, stream>>>(uemb, iemb, P);

    // ---- build row-sorted edge list ----
    hipMemsetAsync(bcnt, 0, NBUCK * sizeof(int), stream);
    k_coarse_hist<<<512, 512, 0, stream>>>(rows, bcnt);
    k_bucket_scan<<<1, 1024, 0, stream>>>(bcnt, bbase, bcur, row_ptr);
    k_coarse_scatter<<<(NNZ + CHUNK - 1) / CHUNK, 512, 0, stream>>>(rows, cols, vals, bcur, edges);
    k_bucket_sort<<<NBUCK, RPB, 0, stream>>>(bbase, edges, row_ptr);

    // ---- factored hops: (I+A)(I+A^2) e ----
    // Y = A*ego + ego;  Z = A*Y;  out = (A*Z + Y)/4
    const int hop_blocks = (NNODES + 31) / 32;   // 8 rows/wave, 4 waves/block
    k_hop<1, false><<<hop_blocks, 256, 0, stream>>>(row_ptr, edges, P, P, Q);        // Y = A e + e
    k_hop<0, false><<<hop_blocks, 256, 0, stream>>>(row_ptr, edges, Q, nullptr, P);  // Z = A Y
    k_hop<1, true ><<<hop_blocks, 256, 0, stream>>>(row_ptr, edges, P, Q, out);      // out = (A Z + Y)/4
}

// Round 12
// 674.238 us; speedup vs baseline: 1.4834x; 1.0631x over previous
//
#include <hip/hip_runtime.h>
#include <stdint.h>

#define NUM_USER 200000
#define NUM_ITEM 400000
#define NNODES   (NUM_USER + NUM_ITEM)   // 600000
#define D        64
#define NNZ      6000000
#define ND       ((size_t)NNODES * D)    // 38.4e6 elements

#define RPB       512                     // rows per bucket
#define NBUCK     ((NNODES + RPB - 1) / RPB)   // 1172
#define CAP       8192                    // max edges staged per bucket (mean 5119)
#define CHUNK     8192                    // edges per block in coarse scatter

typedef float    f4 __attribute__((ext_vector_type(4)));
typedef uint32_t u4 __attribute__((ext_vector_type(4)));

// ---- bf16 helpers (RNE) ----
__device__ __forceinline__ uint32_t bfr(float f) {
    uint32_t u = __float_as_uint(f);
    return (u + 0x7FFFu + ((u >> 16) & 1u)) >> 16;
}
__device__ __forceinline__ uint32_t pack2(float lo, float hi) {
    return (bfr(hi) << 16) | bfr(lo);
}
__device__ __forceinline__ float bl(uint32_t u) { return __uint_as_float(u << 16); }
__device__ __forceinline__ float bh(uint32_t u) { return __uint_as_float(u & 0xFFFF0000u); }

// ---------------- ego -> bf16 table (one pass) ----------------
__global__ void k_cvt(const float* __restrict__ uemb, const float* __restrict__ iemb,
                      u4* __restrict__ ego_bf) {
    long long tid = (long long)blockIdx.x * blockDim.x + threadIdx.x;
    if (tid >= (long long)(ND / 8)) return;
    int node = (int)(tid >> 3);
    int seg = (int)(tid & 7);
    const f4* src = (node < NUM_USER)
        ? (const f4*)uemb + ((size_t)node << 4) + seg * 2
        : (const f4*)iemb + ((size_t)(node - NUM_USER) << 4) + seg * 2;
    f4 a = src[0], b = src[1];
    u4 o;
    o.x = pack2(a.x, a.y); o.y = pack2(a.z, a.w);
    o.z = pack2(b.x, b.y); o.w = pack2(b.z, b.w);
    ego_bf[tid] = o;
}

// ---------------- CSR build: two-level bucket multisplit ----------------

__global__ void k_coarse_hist(const int* __restrict__ rows, int* __restrict__ bcnt) {
    __shared__ int h[NBUCK];
    for (int i = threadIdx.x; i < NBUCK; i += blockDim.x) h[i] = 0;
    __syncthreads();
    int stride = gridDim.x * blockDim.x;
    for (int e = blockIdx.x * blockDim.x + threadIdx.x; e < NNZ; e += stride)
        atomicAdd(&h[rows[e] >> 9], 1);
    __syncthreads();
    for (int i = threadIdx.x; i < NBUCK; i += blockDim.x)
        if (h[i]) atomicAdd(&bcnt[i], h[i]);
}

__global__ void k_bucket_scan(const int* __restrict__ bcnt, int* __restrict__ bbase,
                              int* __restrict__ bcur, int* __restrict__ row_ptr) {
    __shared__ int tsum[1024];
    int t = threadIdx.x;
    int i0 = 2 * t, i1 = 2 * t + 1;
    int c0 = (i0 < NBUCK) ? bcnt[i0] : 0;
    int c1 = (i1 < NBUCK) ? bcnt[i1] : 0;
    tsum[t] = c0 + c1;
    __syncthreads();
    for (int off = 1; off < 1024; off <<= 1) {
        int v = (t >= off) ? tsum[t - off] : 0;
        __syncthreads();
        tsum[t] += v;
        __syncthreads();
    }
    int excl = (t == 0) ? 0 : tsum[t - 1];
    if (i0 < NBUCK) { bbase[i0] = excl;      bcur[i0] = excl; }
    if (i1 < NBUCK) { bbase[i1] = excl + c0; bcur[i1] = excl + c0; }
    if (t == 0) { bbase[NBUCK] = NNZ; row_ptr[NNODES] = NNZ; }
}

__global__ void k_coarse_scatter(const int* __restrict__ rows, const int* __restrict__ cols,
                                 const float* __restrict__ vals, int* __restrict__ bcur,
                                 uint64_t* __restrict__ edges) {
    __shared__ int cnt[NBUCK];
    __shared__ int start[NBUCK];
    int t = threadIdx.x;
    long long base = (long long)blockIdx.x * CHUNK;
    for (int i = t; i < NBUCK; i += blockDim.x) cnt[i] = 0;
    __syncthreads();
    for (int i = t; i < CHUNK; i += blockDim.x) {
        long long e = base + i;
        if (e < NNZ) atomicAdd(&cnt[rows[e] >> 9], 1);
    }
    __syncthreads();
    for (int b = t; b < NBUCK; b += blockDim.x) {
        int c = cnt[b];
        start[b] = c ? atomicAdd(&bcur[b], c) : 0;
    }
    __syncthreads();
    for (int i = t; i < NBUCK; i += blockDim.x) cnt[i] = 0;  // reuse as cursor
    __syncthreads();
    for (int i = t; i < CHUNK; i += blockDim.x) {
        long long e = base + i;
        if (e >= NNZ) continue;
        int r = rows[e];
        int b = r >> 9;
        int pos = start[b] + atomicAdd(&cnt[b], 1);
        uint64_t packed = ((uint64_t)(uint32_t)__float_as_int(vals[e]) << 32)
                        | ((uint64_t)(r & (RPB - 1)) << 20)
                        | (uint32_t)cols[e];
        edges[pos] = packed;
    }
}

__global__ void k_bucket_sort(const int* __restrict__ bbase, uint64_t* __restrict__ edges,
                              int* __restrict__ row_ptr) {
    __shared__ uint64_t stage[CAP];
    __shared__ int hist[RPB];
    __shared__ int cur[RPB];
    int b = blockIdx.x;
    int t = threadIdx.x;
    int bb = bbase[b];
    int cnt = bbase[b + 1] - bb;
    for (int i = t; i < cnt; i += blockDim.x) stage[i] = edges[bb + i];
    for (int i = t; i < RPB; i += blockDim.x) hist[i] = 0;
    __syncthreads();
    for (int i = t; i < cnt; i += blockDim.x)
        atomicAdd(&hist[(uint32_t)(stage[i] >> 20) & (RPB - 1)], 1);
    __syncthreads();
    for (int off = 1; off < RPB; off <<= 1) {
        int v = (t >= off) ? hist[t - off] : 0;
        __syncthreads();
        hist[t] += v;
        __syncthreads();
    }
    int excl = (t == 0) ? 0 : hist[t - 1];
    long long row = (long long)b * RPB + t;
    if (row < NNODES) row_ptr[row] = bb + excl;
    cur[t] = excl;
    __syncthreads();
    for (int i = t; i < cnt; i += blockDim.x) {
        uint64_t e = stage[i];
        int lr = (uint32_t)(e >> 20) & (RPB - 1);
        int pos = atomicAdd(&cur[lr], 1);
        edges[bb + pos] = (e & 0xFFFFFFFF00000000ull) | (e & 0xFFFFFull);
    }
}

// ---------------- fused pull hop: 8 rows/wave, 16-deep single-batch gather ----------------
// Each 8-lane group walks its own row WITHOUT wave-level convergence (__any
// removed: exec-masked divergence only) so nothing blocks load issue. U=16:
// ~97% of rows (Poisson mean 10) complete in ONE batch -> 16 gathers in
// flight per group, one waitcnt, FMAs, store.
// EPI: 0 = none; 1 = add epi_bf[r] (cached); 2 = add epi_bf[r] (NT load).
// dst[r] = (sum_j v_j * src_bf[c_j] (+ epi_bf[r])) * (FINAL ? 0.25 : 1)

template<int EPI, bool FINAL>
__global__ void k_hop(const int* __restrict__ row_ptr,
                      const uint64_t* __restrict__ edges,
                      const u4* __restrict__ src_bf,
                      const u4* __restrict__ epi_bf,
                      void* __restrict__ dst) {
    constexpr int U = 16;
    int wave = (blockIdx.x * blockDim.x + threadIdx.x) >> 6;
    int lane = threadIdx.x & 63;
    int g = lane >> 3;   // row within wave's 8
    int l = lane & 7;    // 16B slot within 128B bf16 row
    int r = wave * 8 + g;
    bool rv = (r < NNODES);
    int beg = rv ? row_ptr[r] : 0;
    int end = rv ? row_ptr[r + 1] : 0;
    float acc0[8], acc1[8];
    #pragma unroll
    for (int k = 0; k < 8; ++k) { acc0[k] = 0.f; acc1[k] = 0.f; }
    for (int j = beg; j < end; j += U) {
        uint64_t cv[U];
        bool act[U];
        #pragma unroll
        for (int u = 0; u < U; ++u) {
            act[u] = (j + u < end);
            if (act[u]) cv[u] = edges[j + u];
        }
        u4 s[U];
        #pragma unroll
        for (int u = 0; u < U; ++u) {
            if (act[u]) s[u] = src_bf[((size_t)((uint32_t)cv[u] & 0xFFFFFu) << 3) + l];
        }
        #pragma unroll
        for (int u = 0; u < U; ++u) {
            if (act[u]) {
                float v = __int_as_float((int)(cv[u] >> 32));
                float* a = (u & 1) ? acc1 : acc0;
                a[0] += v * bl(s[u].x); a[1] += v * bh(s[u].x);
                a[2] += v * bl(s[u].y); a[3] += v * bh(s[u].y);
                a[4] += v * bl(s[u].z); a[5] += v * bh(s[u].z);
                a[6] += v * bl(s[u].w); a[7] += v * bh(s[u].w);
            }
        }
    }
    if (!rv) return;
    float res[8];
    #pragma unroll
    for (int k = 0; k < 8; ++k) res[k] = acc0[k] + acc1[k];
    if (EPI >= 1) {
        u4 eg;
        if (EPI == 2) eg = __builtin_nontemporal_load(epi_bf + ((size_t)r << 3) + l);
        else          eg = epi_bf[((size_t)r << 3) + l];
        res[0] += bl(eg.x); res[1] += bh(eg.x);
        res[2] += bl(eg.y); res[3] += bh(eg.y);
        res[4] += bl(eg.z); res[5] += bh(eg.z);
        res[6] += bl(eg.w); res[7] += bh(eg.w);
    }
    if (FINAL) {
        f4 o0 = {res[0] * 0.25f, res[1] * 0.25f, res[2] * 0.25f, res[3] * 0.25f};
        f4 o1 = {res[4] * 0.25f, res[5] * 0.25f, res[6] * 0.25f, res[7] * 0.25f};
        f4* dp = (f4*)dst + ((size_t)r << 4) + l * 2;
        __builtin_nontemporal_store(o0, dp);
        __builtin_nontemporal_store(o1, dp + 1);
    } else {
        u4 o;
        o.x = pack2(res[0], res[1]); o.y = pack2(res[2], res[3]);
        o.z = pack2(res[4], res[5]); o.w = pack2(res[6], res[7]);
        *((u4*)dst + ((size_t)r << 3) + l) = o;   // cached: a later hop reads this
    }
}

extern "C" void kernel_launch(void* const* d_in, const int* in_sizes, int n_in,
                              void* d_out, int out_size, void* d_ws, size_t ws_size,
                              hipStream_t stream) {
    const float* vals = (const float*)d_in[0];
    const float* uemb = (const float*)d_in[1];
    const float* iemb = (const float*)d_in[2];
    const int*   rows = (const int*)d_in[3];
    const int*   cols = rows + NNZ;

    float* out = (float*)d_out;

    // ---- workspace layout (~205 MB, proven fit) ----
    size_t off = 0;
    char* ws = (char*)d_ws;
    auto take = [&](size_t bytes) { char* p = ws + off; off += (bytes + 255) & ~(size_t)255; return p; };
    u4*       P       = (u4*)take((ND / 8) * sizeof(u4));   // 76.8 MB: ego, then Z
    u4*       Q       = (u4*)take((ND / 8) * sizeof(u4));   // 76.8 MB: Y
    int*      row_ptr = (int*)take((NNODES + 1) * sizeof(int));
    int*      bcnt    = (int*)take(NBUCK * sizeof(int));
    int*      bbase   = (int*)take((NBUCK + 1) * sizeof(int));
    int*      bcur    = (int*)take(NBUCK * sizeof(int));
    uint64_t* edges   = (uint64_t*)take((size_t)NNZ * sizeof(uint64_t));  // 48 MB
    (void)ws_size;

    // ---- ego -> bf16 table ----
    const long long cvt_threads = ND / 8;
    k_cvt<<<(int)((cvt_threads + 255) / 256), 256, 0, stream>>>(uemb, iemb, P);

    // ---- build row-sorted edge list ----
    hipMemsetAsync(bcnt, 0, NBUCK * sizeof(int), stream);
    k_coarse_hist<<<512, 512, 0, stream>>>(rows, bcnt);
    k_bucket_scan<<<1, 1024, 0, stream>>>(bcnt, bbase, bcur, row_ptr);
    k_coarse_scatter<<<(NNZ + CHUNK - 1) / CHUNK, 512, 0, stream>>>(rows, cols, vals, bcur, edges);
    k_bucket_sort<<<NBUCK, RPB, 0, stream>>>(bbase, edges, row_ptr);

    // ---- factored hops: (I+A)(I+A^2) e ----
    // Y = A*ego + ego;  Z = A*Y;  out = (A*Z + Y)/4
    const int hop_blocks = (NNODES + 31) / 32;   // 8 rows/wave, 4 waves/block
    k_hop<1, false><<<hop_blocks, 256, 0, stream>>>(row_ptr, edges, P, P, Q);        // Y = A e + e
    k_hop<0, false><<<hop_blocks, 256, 0, stream>>>(row_ptr, edges, Q, nullptr, P);  // Z = A Y
    k_hop<2, true ><<<hop_blocks, 256, 0, stream>>>(row_ptr, edges, P, Q, out);      // out = (A Z + Y)/4
}

// Round 13
// 612.917 us; speedup vs baseline: 1.6318x; 1.1000x over previous
//
#include <hip/hip_runtime.h>
#include <stdint.h>

#define NUM_USER 200000
#define NUM_ITEM 400000
#define NNODES   (NUM_USER + NUM_ITEM)   // 600000
#define D        64
#define NNZ      6000000
#define ND       ((size_t)NNODES * D)    // 38.4e6 elements

#define RPB       512                     // rows per fine bucket
#define NBUCK     ((NNODES + RPB - 1) / RPB)   // 1172
#define CAP       8192                    // LDS stage cap per fine bucket (mean 5119)
#define NSUP      74                      // super-buckets: row>>13 (8192 rows each)
#define FPS       16                      // fine buckets per super (8192/512)
#define CAP_S     86016                   // slots per super (mean 81081, ~17 sigma)
#define CHUNK1    16384                   // edges per block, pass 1
#define CHUNK2    14336                   // edges per block, pass 2 (6 * 14336 = 86016)

typedef float    f4 __attribute__((ext_vector_type(4)));
typedef uint32_t u4 __attribute__((ext_vector_type(4)));

// ---- bf16 helpers (RNE) ----
__device__ __forceinline__ uint32_t bfr(float f) {
    uint32_t u = __float_as_uint(f);
    return (u + 0x7FFFu + ((u >> 16) & 1u)) >> 16;
}
__device__ __forceinline__ uint32_t pack2(float lo, float hi) {
    return (bfr(hi) << 16) | bfr(lo);
}
__device__ __forceinline__ float bl(uint32_t u) { return __uint_as_float(u << 16); }
__device__ __forceinline__ float bh(uint32_t u) { return __uint_as_float(u & 0xFFFF0000u); }

// ---------------- ego -> bf16 table (one pass) ----------------
__global__ void k_cvt(const float* __restrict__ uemb, const float* __restrict__ iemb,
                      u4* __restrict__ ego_bf) {
    long long tid = (long long)blockIdx.x * blockDim.x + threadIdx.x;
    if (tid >= (long long)(ND / 8)) return;
    int node = (int)(tid >> 3);
    int seg = (int)(tid & 7);
    const f4* src = (node < NUM_USER)
        ? (const f4*)uemb + ((size_t)node << 4) + seg * 2
        : (const f4*)iemb + ((size_t)(node - NUM_USER) << 4) + seg * 2;
    f4 a = src[0], b = src[1];
    u4 o;
    o.x = pack2(a.x, a.y); o.y = pack2(a.z, a.w);
    o.z = pack2(b.x, b.y); o.w = pack2(b.z, b.w);
    ego_bf[tid] = o;
}

// ---------------- CSR build: three-level (super -> fine -> row) ----------------

// init super cursors: scur[s] = s * CAP_S
__global__ void k_init(int* __restrict__ scur) {
    int t = threadIdx.x;
    if (t < NSUP) scur[t] = t * CAP_S;
}

// Pass 1: scatter edges into 74 padded super regions (12B records {row,col,val});
// fused fine-bucket histogram -> bcnt.
__global__ void k_super_scatter(const int* __restrict__ rows, const int* __restrict__ cols,
                                const float* __restrict__ vals,
                                int* __restrict__ scur, int* __restrict__ bcnt,
                                uint32_t* __restrict__ sup) {
    __shared__ int scnt_l[NSUP];
    __shared__ int sstart[NSUP];
    __shared__ int fcnt_l[NBUCK];
    int t = threadIdx.x;
    long long base = (long long)blockIdx.x * CHUNK1;
    for (int i = t; i < NSUP; i += blockDim.x) scnt_l[i] = 0;
    for (int i = t; i < NBUCK; i += blockDim.x) fcnt_l[i] = 0;
    __syncthreads();
    for (int i = t; i < CHUNK1; i += blockDim.x) {
        long long e = base + i;
        if (e < NNZ) {
            int r = rows[e];
            atomicAdd(&scnt_l[r >> 13], 1);
            atomicAdd(&fcnt_l[r >> 9], 1);
        }
    }
    __syncthreads();
    for (int s = t; s < NSUP; s += blockDim.x) {
        int c = scnt_l[s];
        sstart[s] = c ? atomicAdd(&scur[s], c) : 0;
    }
    for (int f = t; f < NBUCK; f += blockDim.x)
        if (fcnt_l[f]) atomicAdd(&bcnt[f], fcnt_l[f]);
    __syncthreads();
    for (int i = t; i < NSUP; i += blockDim.x) scnt_l[i] = 0;   // reuse as cursor
    __syncthreads();
    for (int i = t; i < CHUNK1; i += blockDim.x) {
        long long e = base + i;
        if (e >= NNZ) continue;
        int r = rows[e];
        int s = r >> 13;
        int pos = sstart[s] + atomicAdd(&scnt_l[s], 1);
        uint32_t* p = sup + (size_t)pos * 3;
        p[0] = (uint32_t)r;
        p[1] = (uint32_t)cols[e];
        p[2] = (uint32_t)__float_as_int(vals[e]);
    }
}

// exclusive scan of 1172 fine-bucket counts -> bbase, bcur
__global__ void k_bucket_scan(const int* __restrict__ bcnt, int* __restrict__ bbase,
                              int* __restrict__ bcur, int* __restrict__ row_ptr) {
    __shared__ int tsum[1024];
    int t = threadIdx.x;
    int i0 = 2 * t, i1 = 2 * t + 1;
    int c0 = (i0 < NBUCK) ? bcnt[i0] : 0;
    int c1 = (i1 < NBUCK) ? bcnt[i1] : 0;
    tsum[t] = c0 + c1;
    __syncthreads();
    for (int off = 1; off < 1024; off <<= 1) {
        int v = (t >= off) ? tsum[t - off] : 0;
        __syncthreads();
        tsum[t] += v;
        __syncthreads();
    }
    int excl = (t == 0) ? 0 : tsum[t - 1];
    if (i0 < NBUCK) { bbase[i0] = excl;      bcur[i0] = excl; }
    if (i1 < NBUCK) { bbase[i1] = excl + c0; bcur[i1] = excl + c0; }
    if (t == 0) { bbase[NBUCK] = NNZ; row_ptr[NNODES] = NNZ; }
}

// Pass 2: drain each super region into its 16 fine buckets (packed 8B records).
__global__ void k_fine_scatter(const int* __restrict__ scur, const uint32_t* __restrict__ sup,
                               int* __restrict__ bcur, uint64_t* __restrict__ edges) {
    __shared__ int fcnt_l[FPS];
    __shared__ int fstart[FPS];
    int t = threadIdx.x;
    int s = blockIdx.x / 6;
    int c = blockIdx.x % 6;
    int scnt = scur[s] - s * CAP_S;
    int j0 = c * CHUNK2;
    if (j0 >= scnt) return;                       // uniform across block: safe
    int j1 = min(scnt, j0 + CHUNK2);
    int fine_base = s * FPS;
    const uint32_t* sb = sup + (size_t)s * CAP_S * 3;
    if (t < FPS) fcnt_l[t] = 0;
    __syncthreads();
    for (int i = j0 + t; i < j1; i += blockDim.x)
        atomicAdd(&fcnt_l[(int)(sb[(size_t)i * 3] >> 9) - fine_base], 1);
    __syncthreads();
    if (t < FPS) {
        int cc = fcnt_l[t];
        fstart[t] = cc ? atomicAdd(&bcur[fine_base + t], cc) : 0;
        fcnt_l[t] = 0;                            // reuse as cursor
    }
    __syncthreads();
    for (int i = j0 + t; i < j1; i += blockDim.x) {
        const uint32_t* p = sb + (size_t)i * 3;
        uint32_t r = p[0], col = p[1], vb = p[2];
        int f = (int)(r >> 9) - fine_base;
        int pos = fstart[f] + atomicAdd(&fcnt_l[f], 1);
        edges[pos] = ((uint64_t)vb << 32) | ((uint64_t)(r & (RPB - 1)) << 20) | col;
    }
}

// Fine sort: one block per bucket; stage in LDS, 512-entry hist+scan,
// emit row_ptr and row-sorted edges (local_row stripped) in place.
__global__ void k_bucket_sort(const int* __restrict__ bbase, uint64_t* __restrict__ edges,
                              int* __restrict__ row_ptr) {
    __shared__ uint64_t stage[CAP];
    __shared__ int hist[RPB];
    __shared__ int cur[RPB];
    int b = blockIdx.x;
    int t = threadIdx.x;
    int bb = bbase[b];
    int cnt = bbase[b + 1] - bb;
    for (int i = t; i < cnt; i += blockDim.x) stage[i] = edges[bb + i];
    for (int i = t; i < RPB; i += blockDim.x) hist[i] = 0;
    __syncthreads();
    for (int i = t; i < cnt; i += blockDim.x)
        atomicAdd(&hist[(uint32_t)(stage[i] >> 20) & (RPB - 1)], 1);
    __syncthreads();
    for (int off = 1; off < RPB; off <<= 1) {
        int v = (t >= off) ? hist[t - off] : 0;
        __syncthreads();
        hist[t] += v;
        __syncthreads();
    }
    int excl = (t == 0) ? 0 : hist[t - 1];
    long long row = (long long)b * RPB + t;
    if (row < NNODES) row_ptr[row] = bb + excl;
    cur[t] = excl;
    __syncthreads();
    for (int i = t; i < cnt; i += blockDim.x) {
        uint64_t e = stage[i];
        int lr = (uint32_t)(e >> 20) & (RPB - 1);
        int pos = atomicAdd(&cur[lr], 1);
        edges[bb + pos] = (e & 0xFFFFFFFF00000000ull) | (e & 0xFFFFFull);
    }
}

// ---------------- fused pull hop: 8 rows/wave, 16-deep single-batch gather ----------------
// (unchanged from R12)
template<int EPI, bool FINAL>
__global__ void k_hop(const int* __restrict__ row_ptr,
                      const uint64_t* __restrict__ edges,
                      const u4* __restrict__ src_bf,
                      const u4* __restrict__ epi_bf,
                      void* __restrict__ dst) {
    constexpr int U = 16;
    int wave = (blockIdx.x * blockDim.x + threadIdx.x) >> 6;
    int lane = threadIdx.x & 63;
    int g = lane >> 3;   // row within wave's 8
    int l = lane & 7;    // 16B slot within 128B bf16 row
    int r = wave * 8 + g;
    bool rv = (r < NNODES);
    int beg = rv ? row_ptr[r] : 0;
    int end = rv ? row_ptr[r + 1] : 0;
    float acc0[8], acc1[8];
    #pragma unroll
    for (int k = 0; k < 8; ++k) { acc0[k] = 0.f; acc1[k] = 0.f; }
    for (int j = beg; j < end; j += U) {
        uint64_t cv[U];
        bool act[U];
        #pragma unroll
        for (int u = 0; u < U; ++u) {
            act[u] = (j + u < end);
            if (act[u]) cv[u] = edges[j + u];
        }
        u4 s[U];
        #pragma unroll
        for (int u = 0; u < U; ++u) {
            if (act[u]) s[u] = src_bf[((size_t)((uint32_t)cv[u] & 0xFFFFFu) << 3) + l];
        }
        #pragma unroll
        for (int u = 0; u < U; ++u) {
            if (act[u]) {
                float v = __int_as_float((int)(cv[u] >> 32));
                float* a = (u & 1) ? acc1 : acc0;
                a[0] += v * bl(s[u].x); a[1] += v * bh(s[u].x);
                a[2] += v * bl(s[u].y); a[3] += v * bh(s[u].y);
                a[4] += v * bl(s[u].z); a[5] += v * bh(s[u].z);
                a[6] += v * bl(s[u].w); a[7] += v * bh(s[u].w);
            }
        }
    }
    if (!rv) return;
    float res[8];
    #pragma unroll
    for (int k = 0; k < 8; ++k) res[k] = acc0[k] + acc1[k];
    if (EPI >= 1) {
        u4 eg;
        if (EPI == 2) eg = __builtin_nontemporal_load(epi_bf + ((size_t)r << 3) + l);
        else          eg = epi_bf[((size_t)r << 3) + l];
        res[0] += bl(eg.x); res[1] += bh(eg.x);
        res[2] += bl(eg.y); res[3] += bh(eg.y);
        res[4] += bl(eg.z); res[5] += bh(eg.z);
        res[6] += bl(eg.w); res[7] += bh(eg.w);
    }
    if (FINAL) {
        f4 o0 = {res[0] * 0.25f, res[1] * 0.25f, res[2] * 0.25f, res[3] * 0.25f};
        f4 o1 = {res[4] * 0.25f, res[5] * 0.25f, res[6] * 0.25f, res[7] * 0.25f};
        f4* dp = (f4*)dst + ((size_t)r << 4) + l * 2;
        __builtin_nontemporal_store(o0, dp);
        __builtin_nontemporal_store(o1, dp + 1);
    } else {
        u4 o;
        o.x = pack2(res[0], res[1]); o.y = pack2(res[2], res[3]);
        o.z = pack2(res[4], res[5]); o.w = pack2(res[6], res[7]);
        *((u4*)dst + ((size_t)r << 3) + l) = o;   // cached: a later hop reads this
    }
}

extern "C" void kernel_launch(void* const* d_in, const int* in_sizes, int n_in,
                              void* d_out, int out_size, void* d_ws, size_t ws_size,
                              hipStream_t stream) {
    const float* vals = (const float*)d_in[0];
    const float* uemb = (const float*)d_in[1];
    const float* iemb = (const float*)d_in[2];
    const int*   rows = (const int*)d_in[3];
    const int*   cols = rows + NNZ;

    float* out = (float*)d_out;

    // ---- workspace layout (~205 MB, proven fit) ----
    // Q doubles as the 12B-record super staging area during the CSR build
    // (74 * 86016 * 12B = 76.4 MB <= 76.8 MB), then becomes Y for the hops.
    size_t off = 0;
    char* ws = (char*)d_ws;
    auto take = [&](size_t bytes) { char* p = ws + off; off += (bytes + 255) & ~(size_t)255; return p; };
    u4*       P       = (u4*)take((ND / 8) * sizeof(u4));   // 76.8 MB: ego, then Z
    u4*       Q       = (u4*)take((ND / 8) * sizeof(u4));   // 76.8 MB: sup staging, then Y
    int*      row_ptr = (int*)take((NNODES + 1) * sizeof(int));
    int*      bcnt    = (int*)take(NBUCK * sizeof(int));
    int*      bbase   = (int*)take((NBUCK + 1) * sizeof(int));
    int*      bcur    = (int*)take(NBUCK * sizeof(int));
    int*      scur    = (int*)take(NSUP * sizeof(int));
    uint64_t* edges   = (uint64_t*)take((size_t)NNZ * sizeof(uint64_t));  // 48 MB
    (void)ws_size;
    uint32_t* sup = (uint32_t*)Q;

    // ---- ego -> bf16 table ----
    const long long cvt_threads = ND / 8;
    k_cvt<<<(int)((cvt_threads + 255) / 256), 256, 0, stream>>>(uemb, iemb, P);

    // ---- build row-sorted edge list (super -> fine -> row) ----
    hipMemsetAsync(bcnt, 0, NBUCK * sizeof(int), stream);
    k_init<<<1, 128, 0, stream>>>(scur);
    k_super_scatter<<<(NNZ + CHUNK1 - 1) / CHUNK1, 512, 0, stream>>>(rows, cols, vals, scur, bcnt, sup);
    k_bucket_scan<<<1, 1024, 0, stream>>>(bcnt, bbase, bcur, row_ptr);
    k_fine_scatter<<<NSUP * 6, 512, 0, stream>>>(scur, sup, bcur, edges);
    k_bucket_sort<<<NBUCK, RPB, 0, stream>>>(bbase, edges, row_ptr);

    // ---- factored hops: (I+A)(I+A^2) e ----
    // Y = A*ego + ego;  Z = A*Y;  out = (A*Z + Y)/4
    const int hop_blocks = (NNODES + 31) / 32;   // 8 rows/wave, 4 waves/block
    k_hop<1, false><<<hop_blocks, 256, 0, stream>>>(row_ptr, edges, P, P, Q);        // Y = A e + e
    k_hop<0, false><<<hop_blocks, 256, 0, stream>>>(row_ptr, edges, Q, nullptr, P);  // Z = A Y
    k_hop<2, true ><<<hop_blocks, 256, 0, stream>>>(row_ptr, edges, P, Q, out);      // out = (A Z + Y)/4
}